// Round 2
// baseline (111.277 us; speedup 1.0000x reference)
//
#include <hip/hip_runtime.h>
#include <cstddef>

// ---------------------------------------------------------------------------
// JPEG blockwise 8x8 DCT + quantization.
//   image:          [16, 1, 1024, 1024] fp32
//   quality_factor: [16] fp32
//   out:            [16, 64, 128, 128] fp32, channel c = u*8+v
// out[b, u*8+v, i, j] = (sum_{n,m} C[u,n] C[v,m] (img[b, i*8+n, j*8+m]-128))
//                        / (factor(qf[b]) * Q[u,v])
// Memory-bound: 64 MB in + 64 MB out => ~20 us roofline at 6.3 TB/s.
// ---------------------------------------------------------------------------

// 0.5*cos(m*pi/16) for m = 0..31 (full period table; high-precision literals).
static constexpr float COSTAB[32] = {
     0.50000000000000000f,  0.49039264020161522f,  0.46193976625564337f,
     0.41573480615127262f,  0.35355339059327373f,  0.27778511650980114f,
     0.19134171618254492f,  0.09754516100806417f,  0.00000000000000000f,
    -0.09754516100806417f, -0.19134171618254492f, -0.27778511650980114f,
    -0.35355339059327373f, -0.41573480615127262f, -0.46193976625564337f,
    -0.49039264020161522f, -0.50000000000000000f, -0.49039264020161522f,
    -0.46193976625564337f, -0.41573480615127262f, -0.35355339059327373f,
    -0.27778511650980114f, -0.19134171618254492f, -0.09754516100806417f,
     0.00000000000000000f,  0.09754516100806417f,  0.19134171618254492f,
     0.27778511650980114f,  0.35355339059327373f,  0.41573480615127262f,
     0.46193976625564337f,  0.49039264020161522f,
};

// C[k][n] = a_k * cos(pi*k*(2n+1)/16); a_0 = 1/(2*sqrt(2)), a_k = 1/2.
__device__ __host__ __forceinline__ constexpr float dctC(int k, int n) {
    return (k == 0) ? 0.35355339059327373f
                    : COSTAB[(k * (2 * n + 1)) & 31];
}

static constexpr float LUMQ[64] = {
    16, 11, 10, 16, 24, 40, 51, 61,
    12, 12, 14, 19, 26, 58, 60, 55,
    14, 13, 16, 24, 40, 57, 69, 56,
    14, 17, 22, 29, 51, 87, 80, 62,
    18, 22, 37, 56, 68, 109, 103, 77,
    24, 36, 55, 64, 81, 104, 113, 92,
    49, 64, 78, 87, 103, 121, 120, 101,
    72, 92, 95, 98, 112, 100, 103, 99,
};

// Reference uses Q = LUMQ/100, so 1/Q = 100/LUMQ (compile-time constant).
__device__ __host__ __forceinline__ constexpr float invQ(int u, int v) {
    return 100.0f / LUMQ[u * 8 + v];
}

__global__ __launch_bounds__(256) void jpeg_dct_quant_kernel(
    const float* __restrict__ img,   // [16,1,1024,1024]
    const float* __restrict__ qfv,   // [16]
    float* __restrict__ out)         // [16,64,128,128]
{
    const int bid = blockIdx.x * 256 + threadIdx.x;   // global 8x8-block id
    const int j = bid & 127;           // block col
    const int i = (bid >> 7) & 127;    // block row
    const int b = bid >> 14;           // batch

    const float* src = img + ((size_t)b << 20) + (size_t)(i * 8) * 1024 + j * 8;

    float D[8][8];
    #pragma unroll
    for (int u = 0; u < 8; ++u)
        #pragma unroll
        for (int v = 0; v < 8; ++v)
            D[u][v] = 0.0f;

    #pragma unroll
    for (int n = 0; n < 8; ++n) {
        const float4 r0 = *reinterpret_cast<const float4*>(src + (size_t)n * 1024);
        const float4 r1 = *reinterpret_cast<const float4*>(src + (size_t)n * 1024 + 4);
        const float x[8] = {
            r0.x - 128.0f, r0.y - 128.0f, r0.z - 128.0f, r0.w - 128.0f,
            r1.x - 128.0f, r1.y - 128.0f, r1.z - 128.0f, r1.w - 128.0f,
        };

        // Row DCT: y[v] = sum_m x[m] * C[v][m]   (C folded to literals)
        float y[8];
        #pragma unroll
        for (int v = 0; v < 8; ++v) {
            float acc = 0.0f;
            #pragma unroll
            for (int m = 0; m < 8; ++m)
                acc += x[m] * dctC(v, m);
            y[v] = acc;
        }

        // Column accumulate: D[u][v] += C[u][n] * y[v]
        #pragma unroll
        for (int u = 0; u < 8; ++u) {
            const float cu = dctC(u, n);
            #pragma unroll
            for (int v = 0; v < 8; ++v)
                D[u][v] += cu * y[v];
        }
    }

    // Quantization scale (uniform within the workgroup: b = bid>>14, and one
    // workgroup spans 256 consecutive bids within a single b).
    const float qf = qfv[b];
    const float factor = (qf < 50.0f) ? (5000.0f / qf) : (200.0f - 2.0f * qf);
    const float invf = 1.0f / factor;

    float* dst = out + ((size_t)b << 20) + (size_t)i * 128 + j;
    #pragma unroll
    for (int u = 0; u < 8; ++u)
        #pragma unroll
        for (int v = 0; v < 8; ++v)
            dst[(size_t)(u * 8 + v) * 16384] = D[u][v] * (invf * invQ(u, v));
}

extern "C" void kernel_launch(void* const* d_in, const int* in_sizes, int n_in,
                              void* d_out, int out_size, void* d_ws, size_t ws_size,
                              hipStream_t stream) {
    const float* img = (const float*)d_in[0];   // 16*1024*1024 fp32
    const float* qfv = (const float*)d_in[1];   // 16 fp32
    float* out = (float*)d_out;                 // 16*64*128*128 fp32

    // 16*128*128 = 262144 blocks, one thread each; 256 threads/WG -> 1024 WGs.
    jpeg_dct_quant_kernel<<<1024, 256, 0, stream>>>(img, qfv, out);
}